// Round 1
// baseline (249.435 us; speedup 1.0000x reference)
//
#include <hip/hip_runtime.h>
#include <hip/hip_bf16.h>
#include <cstdint>

typedef unsigned short u16;
typedef __attribute__((ext_vector_type(8))) short short8;   // 8 bf16 (4 VGPRs) MFMA A/B frag
typedef __attribute__((ext_vector_type(4))) float f32x4;    // MFMA C/D frag
typedef __attribute__((ext_vector_type(4))) unsigned int u32x4;
typedef __attribute__((ext_vector_type(4))) unsigned short u16x4;

// ---------- helpers ----------
__device__ __forceinline__ u16 f2b(float x) {
    union { float f; unsigned int u; } v; v.f = x;
    unsigned int u = v.u;
    u += 0x7FFFu + ((u >> 16) & 1u);   // round-to-nearest-even
    return (u16)(u >> 16);
}

// ---------- f32 -> bf16 conversion (select source by blockIdx.z) ----------
__global__ __launch_bounds__(256) void cvt_k(const float* __restrict__ s0,
                                             const float* __restrict__ s1,
                                             const float* __restrict__ s2,
                                             const float* __restrict__ s3,
                                             u16* __restrict__ dst, int per) {
    const float* s = (blockIdx.z == 0) ? s0 : (blockIdx.z == 1) ? s1
                   : (blockIdx.z == 2) ? s2 : s3;
    int i = (blockIdx.x * 256 + threadIdx.x) * 4;
    float4 v = *(const float4*)&s[i];
    u16x4 o = { f2b(v.x), f2b(v.y), f2b(v.z), f2b(v.w) };
    *(u16x4*)&dst[(size_t)blockIdx.z * per + i] = o;
}

// ---------- geometry log-bias: out[b,h,i,j] = log(max(relu(emb@WG+bG),1e-6)) ----------
__global__ __launch_bounds__(256) void geom_k(const float* __restrict__ box,
                                              const float* __restrict__ WG,
                                              const float* __restrict__ bG,
                                              float* __restrict__ out) {
    const float c_dim[8] = {1.0f, 0.42169650f, 0.17782794f, 0.074989421f,
                            0.031622777f, 0.013335214f, 0.0056234132f, 0.0023713737f};
    int pidx = blockIdx.x * 256 + threadIdx.x;      // pair index over B*N*N
    int b = pidx >> 18;
    int rem = pidx & 262143;
    int i = rem >> 9, j = rem & 511;

    float4 bi = *(const float4*)&box[(size_t)(((b << 9) + i) << 2)];
    float4 bj = *(const float4*)&box[(size_t)(((b << 9) + j) << 2)];
    float cxi = (bi.x + bi.z) * 0.5f, cyi = (bi.y + bi.w) * 0.5f;
    float wi = bi.z - bi.x + 1.0f,    hi = bi.w - bi.y + 1.0f;
    float cxj = (bj.x + bj.z) * 0.5f, cyj = (bj.y + bj.w) * 0.5f;
    float wj = bj.z - bj.x + 1.0f,    hj = bj.w - bj.y + 1.0f;

    float pos[4];
    pos[0] = logf(fmaxf(fabsf((cxi - cxj) / wi), 1e-3f));
    pos[1] = logf(fmaxf(fabsf((cyi - cyj) / hi), 1e-3f));
    pos[2] = logf(wi / wj);
    pos[3] = logf(hi / hj);

    float acc[8] = {0.f, 0.f, 0.f, 0.f, 0.f, 0.f, 0.f, 0.f};
#pragma unroll
    for (int p = 0; p < 4; p++) {
        float base = 100.0f * pos[p];
#pragma unroll
        for (int f = 0; f < 8; f++) {
            float ang = base * c_dim[f];
            float sv = __sinf(ang), cv = __cosf(ang);
            int g = (p << 3) + f;           // sin feature index; cos = g+32
            // wave-uniform indices -> scalar loads through K$
#pragma unroll
            for (int h = 0; h < 8; h++) {
                acc[h] += sv * WG[h * 64 + g] + cv * WG[h * 64 + 32 + g];
            }
        }
    }
    int obase = (b << 21) + (i << 9) + j;   // [B,H,N,N]
#pragma unroll
    for (int h = 0; h < 8; h++) {
        float z = acc[h] + bG[h];
        out[(size_t)obase + ((size_t)h << 18)] = logf(fmaxf(z, 1e-6f));
    }
}

// ---------- generic bf16 MFMA GEMM: C[M,N] = A[M,K] @ Bm[N,K]^T (+epilogue) ----------
// MODE 0: proj -> q/k bf16 [B,H,N,DK]      (M=2048,N=512,K=512, +bias)
// MODE 1: proj -> vT bf16 [B,H,DK,N]       (same dims, +bias)
// MODE 2: scores -> S f32 += 0.125*acc     (per z=(b,h): M=N=512,K=64, in-place over wglog)
// MODE 3: PV -> attn bf16 [B,N,H*DK]       (per z: M=512,N=64,K=512)
// MODE 4: out -> f32 row-major [2048,512]  (+bias)
template<int MODE>
__global__ __launch_bounds__(256) void gemm_k(const u16* __restrict__ A,
                                              const u16* __restrict__ Bm,
                                              const float* __restrict__ bias,
                                              void* __restrict__ outp) {
    constexpr int Kdim = (MODE == 2) ? 64 : 512;
    constexpr int lda  = (MODE == 2) ? 64 : 512;
    constexpr int ldb  = (MODE == 2) ? 64 : 512;

    __shared__ u16 As[64 * 32];
    __shared__ u16 Bs[64 * 32];

    const int t = threadIdx.x;
    const int wave = t >> 6, lane = t & 63;
    const int wr = wave >> 1, wc = wave & 1;
    const int m0 = blockIdx.y * 64, n0 = blockIdx.x * 64;
    const int z = blockIdx.z;

    const u16* Ab = A;
    const u16* Bb = Bm;
    if constexpr (MODE == 2) { Ab = A + (size_t)z * 512 * 64;  Bb = Bm + (size_t)z * 512 * 64; }
    if constexpr (MODE == 3) { Ab = A + (size_t)z * 512 * 512; Bb = Bm + (size_t)z * 64 * 512; }

    f32x4 acc[2][2] = {};
    const int srow = t >> 2, scol = (t & 3) * 8;

    for (int k0 = 0; k0 < Kdim; k0 += 32) {
        *(u32x4*)&As[srow * 32 + scol] = *(const u32x4*)&Ab[(size_t)(m0 + srow) * lda + k0 + scol];
        *(u32x4*)&Bs[srow * 32 + scol] = *(const u32x4*)&Bb[(size_t)(n0 + srow) * ldb + k0 + scol];
        __syncthreads();

        short8 af[2], bfr[2];
#pragma unroll
        for (int i = 0; i < 2; i++)
            af[i] = *(const short8*)&As[(wr * 32 + i * 16 + (lane & 15)) * 32 + ((lane >> 4) << 3)];
#pragma unroll
        for (int jj = 0; jj < 2; jj++)
            bfr[jj] = *(const short8*)&Bs[(wc * 32 + jj * 16 + (lane & 15)) * 32 + ((lane >> 4) << 3)];
#pragma unroll
        for (int i = 0; i < 2; i++)
#pragma unroll
            for (int jj = 0; jj < 2; jj++)
                acc[i][jj] = __builtin_amdgcn_mfma_f32_16x16x32_bf16(af[i], bfr[jj], acc[i][jj], 0, 0, 0);
        __syncthreads();
    }

    u16*  outU = (u16*)outp;
    float* outF = (float*)outp;
#pragma unroll
    for (int i = 0; i < 2; i++) {
#pragma unroll
        for (int jj = 0; jj < 2; jj++) {
#pragma unroll
            for (int r = 0; r < 4; r++) {
                int row = m0 + wr * 32 + i * 16 + ((lane >> 4) << 2) + r;
                int col = n0 + wc * 32 + jj * 16 + (lane & 15);
                float v = acc[i][jj][r];
                if constexpr (MODE == 0) {
                    int b = row >> 9, rr = row & 511, h = col >> 6, d = col & 63;
                    outU[(size_t)((((b << 3) + h) << 9) + rr) * 64 + d] = f2b(v + bias[col]);
                } else if constexpr (MODE == 1) {
                    int b = row >> 9, rr = row & 511, h = col >> 6, d = col & 63;
                    outU[(size_t)((((b << 3) + h) << 6) + d) * 512 + rr] = f2b(v + bias[col]);
                } else if constexpr (MODE == 2) {
                    size_t idx = ((size_t)z << 18) + ((size_t)row << 9) + col;
                    outF[idx] = v * 0.125f + outF[idx];
                } else if constexpr (MODE == 3) {
                    int b = z >> 3, h = z & 7;
                    outU[(size_t)(((b << 9) + row) << 9) + (h << 6) + col] = f2b(v);
                } else {
                    outF[((size_t)row << 9) + col] = v + bias[col];
                }
            }
        }
    }
}

// ---------- row softmax over S[16384][512] f32 -> P bf16 ----------
__global__ __launch_bounds__(256) void softmax_k(const float* __restrict__ S,
                                                 u16* __restrict__ P) {
    __shared__ float red[8];
    int row = blockIdx.x;
    const float* src = S + (size_t)row * 512;
    int t = threadIdx.x, wave = t >> 6, lane = t & 63;

    float x0 = src[t], x1 = src[t + 256];
    float m = fmaxf(x0, x1);
#pragma unroll
    for (int off = 32; off; off >>= 1) m = fmaxf(m, __shfl_xor(m, off));
    if (lane == 0) red[wave] = m;
    __syncthreads();
    m = fmaxf(fmaxf(red[0], red[1]), fmaxf(red[2], red[3]));

    float e0 = __expf(x0 - m), e1 = __expf(x1 - m);
    float s = e0 + e1;
#pragma unroll
    for (int off = 32; off; off >>= 1) s += __shfl_xor(s, off);
    if (lane == 0) red[4 + wave] = s;
    __syncthreads();
    s = red[4] + red[5] + red[6] + red[7];
    float inv = 1.0f / s;
    P[(size_t)row * 512 + t]       = f2b(e0 * inv);
    P[(size_t)row * 512 + t + 256] = f2b(e1 * inv);
}

// ---------- launch ----------
extern "C" void kernel_launch(void* const* d_in, const int* in_sizes, int n_in,
                              void* d_out, int out_size, void* d_ws, size_t ws_size,
                              hipStream_t stream) {
    const float* inq = (const float*)d_in[0];
    const float* ink = (const float*)d_in[1];
    const float* inv = (const float*)d_in[2];
    const float* box = (const float*)d_in[3];
    const float* Wq  = (const float*)d_in[4];
    const float* bq  = (const float*)d_in[5];
    const float* Wk  = (const float*)d_in[6];
    const float* bk  = (const float*)d_in[7];
    const float* Wv  = (const float*)d_in[8];
    const float* bv  = (const float*)d_in[9];
    const float* Wo  = (const float*)d_in[10];
    const float* bo  = (const float*)d_in[11];
    const float* WG  = (const float*)d_in[12];
    const float* bG  = (const float*)d_in[13];

    // workspace layout (u16 element offsets); total = 64 MiB
    u16* base = (u16*)d_ws;
    u16* XQ  = base;                 // 3 x 1,048,576 bf16
    u16* XK  = base + 1048576;
    u16* XV  = base + 2097152;
    u16* WQb = base + 3145728;       // 4 x 262,144 bf16
    u16* WKb = base + 3407872;
    u16* WVb = base + 3670016;
    u16* WOb = base + 3932160;
    u16* Qb  = base + 4194304;       // [B,H,N,64] bf16
    u16* Kb  = base + 5242880;       // [B,H,N,64] bf16
    u16* VT  = base + 6291456;       // [B,H,64,N] bf16
    u16* ATT = base + 7340032;       // [B,N,512] bf16
    float* Sf = (float*)(base + 8388608);        // [B,H,N,N] f32 (wglog then scores)
    u16* Pb  = base + 25165824;                  // [B,H,N,N] bf16

    cvt_k<<<dim3(1024, 1, 3), 256, 0, stream>>>(inq, ink, inv, inq, XQ, 1048576);
    cvt_k<<<dim3(256, 1, 4), 256, 0, stream>>>(Wq, Wk, Wv, Wo, WQb, 262144);
    geom_k<<<dim3(4096), 256, 0, stream>>>(box, WG, bG, Sf);

    gemm_k<0><<<dim3(8, 32, 1), 256, 0, stream>>>(XQ, WQb, bq, Qb);
    gemm_k<0><<<dim3(8, 32, 1), 256, 0, stream>>>(XK, WKb, bk, Kb);
    gemm_k<1><<<dim3(8, 32, 1), 256, 0, stream>>>(XV, WVb, bv, VT);

    gemm_k<2><<<dim3(8, 8, 32), 256, 0, stream>>>(Qb, Kb, nullptr, Sf);
    softmax_k<<<dim3(16384), 256, 0, stream>>>(Sf, Pb);
    gemm_k<3><<<dim3(1, 8, 32), 256, 0, stream>>>(Pb, VT, nullptr, ATT);
    gemm_k<4><<<dim3(8, 32, 1), 256, 0, stream>>>(ATT, WOb, bo, d_out);
}

// Round 2
// 110.364 us; speedup vs baseline: 2.2601x; 2.2601x over previous
//
#include <hip/hip_runtime.h>
#include <hip/hip_bf16.h>
#include <cstdint>

typedef unsigned short u16;
typedef unsigned int u32;
typedef __attribute__((ext_vector_type(8))) short short8;   // 8 bf16 (4 VGPRs) MFMA A/B frag
typedef __attribute__((ext_vector_type(4))) float f32x4;    // MFMA C/D frag
typedef __attribute__((ext_vector_type(4))) unsigned int u32x4;
typedef __attribute__((ext_vector_type(4))) unsigned short u16x4;

// ---------- helpers ----------
__device__ __forceinline__ u16 f2b(float x) {
    union { float f; unsigned int u; } v; v.f = x;
    unsigned int u = v.u;
    u += 0x7FFFu + ((u >> 16) & 1u);   // round-to-nearest-even
    return (u16)(u >> 16);
}

// ---------- f32 -> bf16 conversion (select source by blockIdx.z) ----------
__global__ __launch_bounds__(256) void cvt_k(const float* __restrict__ s0,
                                             const float* __restrict__ s1,
                                             const float* __restrict__ s2,
                                             const float* __restrict__ s3,
                                             u16* __restrict__ dst, int per) {
    const float* s = (blockIdx.z == 0) ? s0 : (blockIdx.z == 1) ? s1
                   : (blockIdx.z == 2) ? s2 : s3;
    int i = (blockIdx.x * 256 + threadIdx.x) * 4;
    float4 v = *(const float4*)&s[i];
    u16x4 o = { f2b(v.x), f2b(v.y), f2b(v.z), f2b(v.w) };
    *(u16x4*)&dst[(size_t)blockIdx.z * per + i] = o;
}

// ---------- geometry log-bias v2: MFMA over bf16 embedding ----------
// Each block: one (b, i, jt); 256 pairs (j = jt*256 + t). Thread t computes the
// 64-dim trig embedding for its pair -> bf16 in LDS (XOR-swizzled rows), then
// 4 waves run emb[256x64] @ WG'[16x64]^T via 16x16x32 MFMA (heads padded to 16).
// Epilogue: log(max(z+bias,1e-6)) -> Sf[b,h,i,j].
__global__ __launch_bounds__(256) void geom_k(const float* __restrict__ box,
                                              const float* __restrict__ WG,
                                              const float* __restrict__ bG,
                                              float* __restrict__ out) {
    __shared__ char embs[256 * 128];   // [256 pairs][64 bf16] rows, 128B each

    const float c_dim[8] = {1.0f, 0.42169650f, 0.17782794f, 0.074989421f,
                            0.031622777f, 0.013335214f, 0.0056234132f, 0.0023713737f};
    const int t = threadIdx.x;
    const int wave = t >> 6, lane = t & 63;
    const int jt = blockIdx.x, i = blockIdx.y, b = blockIdx.z;
    const int j = (jt << 8) + t;

    // ---- per-pair geometry ----
    float4 bi = *(const float4*)&box[(size_t)(((b << 9) + i) << 2)];
    float4 bj = *(const float4*)&box[(size_t)(((b << 9) + j) << 2)];
    float cxi = (bi.x + bi.z) * 0.5f, cyi = (bi.y + bi.w) * 0.5f;
    float wi = bi.z - bi.x + 1.0f,    hgt_i = bi.w - bi.y + 1.0f;
    float cxj = (bj.x + bj.z) * 0.5f, cyj = (bj.y + bj.w) * 0.5f;
    float wj = bj.z - bj.x + 1.0f,    hgt_j = bj.w - bj.y + 1.0f;

    float pos[4];
    pos[0] = __logf(fmaxf(fabsf((cxi - cxj) / wi), 1e-3f));
    pos[1] = __logf(fmaxf(fabsf((cyi - cyj) / hgt_i), 1e-3f));
    pos[2] = __logf(wi) - __logf(wj);
    pos[3] = __logf(hgt_i) - __logf(hgt_j);

    // ---- 64-dim embedding -> LDS bf16, XOR-swizzled rows ----
#pragma unroll
    for (int p = 0; p < 4; p++) {
        float base = 100.0f * pos[p];
        u32x4 sp, cp;
#pragma unroll
        for (int f = 0; f < 4; f++) {
            float a0 = base * c_dim[2 * f], a1 = base * c_dim[2 * f + 1];
            sp[f] = (u32)f2b(__sinf(a0)) | ((u32)f2b(__sinf(a1)) << 16);
            cp[f] = (u32)f2b(__cosf(a0)) | ((u32)f2b(__cosf(a1)) << 16);
        }
        int swz = (t & 7) << 4;
        *(u32x4*)(embs + (((t << 7) + (p << 4)) ^ swz)) = sp;           // sin cols p*8..
        *(u32x4*)(embs + (((t << 7) + 64 + (p << 4)) ^ swz)) = cp;      // cos cols 32+p*8..
    }

    // ---- B-fragments: WG' [16 heads(pad)][64] from global f32, once per wave ----
    const int h = lane & 15;            // B-frag col = head; also A-frag row-in-tile
    const int ko = (lane >> 4) << 3;    // k-offset within 32-wide K step
    short8 bf0 = {0, 0, 0, 0, 0, 0, 0, 0};
    short8 bf1 = {0, 0, 0, 0, 0, 0, 0, 0};
    float bGh = 0.0f;
    if (h < 8) {
        const float* wrow = WG + h * 64;
#pragma unroll
        for (int e = 0; e < 8; e++) {
            bf0[e] = (short)f2b(wrow[ko + e]);
            bf1[e] = (short)f2b(wrow[32 + ko + e]);
        }
        bGh = bG[h];
    }
    __syncthreads();

    // ---- MFMA: 4 M-tiles per wave, K=64 in two 32-steps ----
#pragma unroll
    for (int tt = 0; tt < 4; tt++) {
        int mt = (wave << 2) + tt;
        int row = (mt << 4) + h;
        int rswz = (row & 7) << 4;
        short8 a0 = *(const short8*)(embs + (((row << 7) + (ko << 1)) ^ rswz));
        short8 a1 = *(const short8*)(embs + (((row << 7) + 64 + (ko << 1)) ^ rswz));
        f32x4 acc = {0.f, 0.f, 0.f, 0.f};
        acc = __builtin_amdgcn_mfma_f32_16x16x32_bf16(a0, bf0, acc, 0, 0, 0);
        acc = __builtin_amdgcn_mfma_f32_16x16x32_bf16(a1, bf1, acc, 0, 0, 0);

        if (h < 8) {
            int j0 = (jt << 8) + (mt << 4) + ((lane >> 4) << 2);
            float4 o;
            o.x = __logf(fmaxf(acc[0] + bGh, 1e-6f));
            o.y = __logf(fmaxf(acc[1] + bGh, 1e-6f));
            o.z = __logf(fmaxf(acc[2] + bGh, 1e-6f));
            o.w = __logf(fmaxf(acc[3] + bGh, 1e-6f));
            *(float4*)&out[((size_t)((b << 3) + h) << 18) + ((size_t)i << 9) + j0] = o;
        }
    }
}

// ---------- generic bf16 MFMA GEMM: C[M,N] = A[M,K] @ Bm[N,K]^T (+epilogue) ----------
// MODE 0: proj -> q/k bf16 [B,H,N,DK]      (M=2048,N=512,K=512, +bias)
// MODE 1: proj -> vT bf16 [B,H,DK,N]       (same dims, +bias)
// MODE 2: scores -> S f32 += 0.125*acc     (per z=(b,h): M=N=512,K=64, in-place over wglog)
// MODE 3: PV -> attn bf16 [B,N,H*DK]       (per z: M=512,N=64,K=512)
// MODE 4: out -> f32 row-major [2048,512]  (+bias)
template<int MODE>
__global__ __launch_bounds__(256) void gemm_k(const u16* __restrict__ A,
                                              const u16* __restrict__ Bm,
                                              const float* __restrict__ bias,
                                              void* __restrict__ outp) {
    constexpr int Kdim = (MODE == 2) ? 64 : 512;
    constexpr int lda  = (MODE == 2) ? 64 : 512;
    constexpr int ldb  = (MODE == 2) ? 64 : 512;

    __shared__ u16 As[64 * 32];
    __shared__ u16 Bs[64 * 32];

    const int t = threadIdx.x;
    const int wave = t >> 6, lane = t & 63;
    const int wr = wave >> 1, wc = wave & 1;
    const int m0 = blockIdx.y * 64, n0 = blockIdx.x * 64;
    const int z = blockIdx.z;

    const u16* Ab = A;
    const u16* Bb = Bm;
    if constexpr (MODE == 2) { Ab = A + (size_t)z * 512 * 64;  Bb = Bm + (size_t)z * 512 * 64; }
    if constexpr (MODE == 3) { Ab = A + (size_t)z * 512 * 512; Bb = Bm + (size_t)z * 64 * 512; }

    f32x4 acc[2][2] = {};
    const int srow = t >> 2, scol = (t & 3) * 8;

    for (int k0 = 0; k0 < Kdim; k0 += 32) {
        *(u32x4*)&As[srow * 32 + scol] = *(const u32x4*)&Ab[(size_t)(m0 + srow) * lda + k0 + scol];
        *(u32x4*)&Bs[srow * 32 + scol] = *(const u32x4*)&Bb[(size_t)(n0 + srow) * ldb + k0 + scol];
        __syncthreads();

        short8 af[2], bfr[2];
#pragma unroll
        for (int i = 0; i < 2; i++)
            af[i] = *(const short8*)&As[(wr * 32 + i * 16 + (lane & 15)) * 32 + ((lane >> 4) << 3)];
#pragma unroll
        for (int jj = 0; jj < 2; jj++)
            bfr[jj] = *(const short8*)&Bs[(wc * 32 + jj * 16 + (lane & 15)) * 32 + ((lane >> 4) << 3)];
#pragma unroll
        for (int i = 0; i < 2; i++)
#pragma unroll
            for (int jj = 0; jj < 2; jj++)
                acc[i][jj] = __builtin_amdgcn_mfma_f32_16x16x32_bf16(af[i], bfr[jj], acc[i][jj], 0, 0, 0);
        __syncthreads();
    }

    u16*  outU = (u16*)outp;
    float* outF = (float*)outp;
#pragma unroll
    for (int i = 0; i < 2; i++) {
#pragma unroll
        for (int jj = 0; jj < 2; jj++) {
#pragma unroll
            for (int r = 0; r < 4; r++) {
                int row = m0 + wr * 32 + i * 16 + ((lane >> 4) << 2) + r;
                int col = n0 + wc * 32 + jj * 16 + (lane & 15);
                float v = acc[i][jj][r];
                if constexpr (MODE == 0) {
                    int b = row >> 9, rr = row & 511, h = col >> 6, d = col & 63;
                    outU[(size_t)((((b << 3) + h) << 9) + rr) * 64 + d] = f2b(v + bias[col]);
                } else if constexpr (MODE == 1) {
                    int b = row >> 9, rr = row & 511, h = col >> 6, d = col & 63;
                    outU[(size_t)((((b << 3) + h) << 6) + d) * 512 + rr] = f2b(v + bias[col]);
                } else if constexpr (MODE == 2) {
                    size_t idx = ((size_t)z << 18) + ((size_t)row << 9) + col;
                    outF[idx] = v * 0.125f + outF[idx];
                } else if constexpr (MODE == 3) {
                    int b = z >> 3, h = z & 7;
                    outU[(size_t)(((b << 9) + row) << 9) + (h << 6) + col] = f2b(v);
                } else {
                    outF[((size_t)row << 9) + col] = v + bias[col];
                }
            }
        }
    }
}

// ---------- row softmax over S[16384][512] f32 -> P bf16 ----------
__global__ __launch_bounds__(256) void softmax_k(const float* __restrict__ S,
                                                 u16* __restrict__ P) {
    __shared__ float red[8];
    int row = blockIdx.x;
    const float* src = S + (size_t)row * 512;
    int t = threadIdx.x, wave = t >> 6, lane = t & 63;

    float x0 = src[t], x1 = src[t + 256];
    float m = fmaxf(x0, x1);
#pragma unroll
    for (int off = 32; off; off >>= 1) m = fmaxf(m, __shfl_xor(m, off));
    if (lane == 0) red[wave] = m;
    __syncthreads();
    m = fmaxf(fmaxf(red[0], red[1]), fmaxf(red[2], red[3]));

    float e0 = __expf(x0 - m), e1 = __expf(x1 - m);
    float s = e0 + e1;
#pragma unroll
    for (int off = 32; off; off >>= 1) s += __shfl_xor(s, off);
    if (lane == 0) red[4 + wave] = s;
    __syncthreads();
    s = red[4] + red[5] + red[6] + red[7];
    float inv = 1.0f / s;
    P[(size_t)row * 512 + t]       = f2b(e0 * inv);
    P[(size_t)row * 512 + t + 256] = f2b(e1 * inv);
}

// ---------- launch ----------
extern "C" void kernel_launch(void* const* d_in, const int* in_sizes, int n_in,
                              void* d_out, int out_size, void* d_ws, size_t ws_size,
                              hipStream_t stream) {
    const float* inq = (const float*)d_in[0];
    const float* ink = (const float*)d_in[1];
    const float* inv = (const float*)d_in[2];
    const float* box = (const float*)d_in[3];
    const float* Wq  = (const float*)d_in[4];
    const float* bq  = (const float*)d_in[5];
    const float* Wk  = (const float*)d_in[6];
    const float* bk  = (const float*)d_in[7];
    const float* Wv  = (const float*)d_in[8];
    const float* bv  = (const float*)d_in[9];
    const float* Wo  = (const float*)d_in[10];
    const float* bo  = (const float*)d_in[11];
    const float* WG  = (const float*)d_in[12];
    const float* bG  = (const float*)d_in[13];

    // workspace layout (u16 element offsets); total = 64 MiB
    u16* base = (u16*)d_ws;
    u16* XQ  = base;                 // 3 x 1,048,576 bf16
    u16* XK  = base + 1048576;
    u16* XV  = base + 2097152;
    u16* WQb = base + 3145728;       // 4 x 262,144 bf16
    u16* WKb = base + 3407872;
    u16* WVb = base + 3670016;
    u16* WOb = base + 3932160;
    u16* Qb  = base + 4194304;       // [B,H,N,64] bf16
    u16* Kb  = base + 5242880;       // [B,H,N,64] bf16
    u16* VT  = base + 6291456;       // [B,H,64,N] bf16
    u16* ATT = base + 7340032;       // [B,N,512] bf16
    float* Sf = (float*)(base + 8388608);        // [B,H,N,N] f32 (wglog then scores)
    u16* Pb  = base + 25165824;                  // [B,H,N,N] bf16

    cvt_k<<<dim3(1024, 1, 3), 256, 0, stream>>>(inq, ink, inv, inq, XQ, 1048576);
    cvt_k<<<dim3(256, 1, 4), 256, 0, stream>>>(Wq, Wk, Wv, Wo, WQb, 262144);
    geom_k<<<dim3(2, 512, 4), 256, 0, stream>>>(box, WG, bG, Sf);

    gemm_k<0><<<dim3(8, 32, 1), 256, 0, stream>>>(XQ, WQb, bq, Qb);
    gemm_k<0><<<dim3(8, 32, 1), 256, 0, stream>>>(XK, WKb, bk, Kb);
    gemm_k<1><<<dim3(8, 32, 1), 256, 0, stream>>>(XV, WVb, bv, VT);

    gemm_k<2><<<dim3(8, 8, 32), 256, 0, stream>>>(Qb, Kb, nullptr, Sf);
    softmax_k<<<dim3(16384), 256, 0, stream>>>(Sf, Pb);
    gemm_k<3><<<dim3(1, 8, 32), 256, 0, stream>>>(Pb, VT, nullptr, ATT);
    gemm_k<4><<<dim3(8, 32, 1), 256, 0, stream>>>(ATT, WOb, bo, d_out);
}

// Round 3
// 91.648 us; speedup vs baseline: 2.7217x; 1.2042x over previous
//
#include <hip/hip_runtime.h>
#include <hip/hip_bf16.h>
#include <cstdint>

typedef unsigned short u16;
typedef unsigned int u32;
typedef __attribute__((ext_vector_type(8))) short short8;   // 8 bf16 (4 VGPRs) MFMA A/B frag
typedef __attribute__((ext_vector_type(4))) float f32x4;    // MFMA C/D frag
typedef __attribute__((ext_vector_type(4))) unsigned int u32x4;
typedef __attribute__((ext_vector_type(4))) unsigned short u16x4;

// ---------- helpers ----------
__device__ __forceinline__ u16 f2b(float x) {
    union { float f; unsigned int u; } v; v.f = x;
    unsigned int u = v.u;
    u += 0x7FFFu + ((u >> 16) & 1u);   // round-to-nearest-even
    return (u16)(u >> 16);
}

// ---------- f32 -> bf16 conversion (select source by blockIdx.z) ----------
__global__ __launch_bounds__(256) void cvt_k(const float* __restrict__ s0,
                                             const float* __restrict__ s1,
                                             const float* __restrict__ s2,
                                             const float* __restrict__ s3,
                                             u16* __restrict__ dst, int per) {
    const float* s = (blockIdx.z == 0) ? s0 : (blockIdx.z == 1) ? s1
                   : (blockIdx.z == 2) ? s2 : s3;
    int i = (blockIdx.x * 256 + threadIdx.x) * 4;
    float4 v = *(const float4*)&s[i];
    u16x4 o = { f2b(v.x), f2b(v.y), f2b(v.z), f2b(v.w) };
    *(u16x4*)&dst[(size_t)blockIdx.z * per + i] = o;
}

// ---------- geometry log-bias: MFMA over bf16 embedding ----------
__global__ __launch_bounds__(256) void geom_k(const float* __restrict__ box,
                                              const float* __restrict__ WG,
                                              const float* __restrict__ bG,
                                              float* __restrict__ out) {
    __shared__ char embs[256 * 128];   // [256 pairs][64 bf16] rows, 128B each

    const float c_dim[8] = {1.0f, 0.42169650f, 0.17782794f, 0.074989421f,
                            0.031622777f, 0.013335214f, 0.0056234132f, 0.0023713737f};
    const int t = threadIdx.x;
    const int wave = t >> 6, lane = t & 63;
    const int jt = blockIdx.x, i = blockIdx.y, b = blockIdx.z;
    const int j = (jt << 8) + t;

    float4 bi = *(const float4*)&box[(size_t)(((b << 9) + i) << 2)];
    float4 bj = *(const float4*)&box[(size_t)(((b << 9) + j) << 2)];
    float cxi = (bi.x + bi.z) * 0.5f, cyi = (bi.y + bi.w) * 0.5f;
    float wi = bi.z - bi.x + 1.0f,    hgt_i = bi.w - bi.y + 1.0f;
    float cxj = (bj.x + bj.z) * 0.5f, cyj = (bj.y + bj.w) * 0.5f;
    float wj = bj.z - bj.x + 1.0f,    hgt_j = bj.w - bj.y + 1.0f;

    float pos[4];
    pos[0] = __logf(fmaxf(fabsf((cxi - cxj) / wi), 1e-3f));
    pos[1] = __logf(fmaxf(fabsf((cyi - cyj) / hgt_i), 1e-3f));
    pos[2] = __logf(wi) - __logf(wj);
    pos[3] = __logf(hgt_i) - __logf(hgt_j);

#pragma unroll
    for (int p = 0; p < 4; p++) {
        float base = 100.0f * pos[p];
        u32x4 sp, cp;
#pragma unroll
        for (int f = 0; f < 4; f++) {
            float a0 = base * c_dim[2 * f], a1 = base * c_dim[2 * f + 1];
            sp[f] = (u32)f2b(__sinf(a0)) | ((u32)f2b(__sinf(a1)) << 16);
            cp[f] = (u32)f2b(__cosf(a0)) | ((u32)f2b(__cosf(a1)) << 16);
        }
        int swz = (t & 7) << 4;
        *(u32x4*)(embs + (((t << 7) + (p << 4)) ^ swz)) = sp;
        *(u32x4*)(embs + (((t << 7) + 64 + (p << 4)) ^ swz)) = cp;
    }

    const int h = lane & 15;
    const int ko = (lane >> 4) << 3;
    short8 bf0 = {0, 0, 0, 0, 0, 0, 0, 0};
    short8 bf1 = {0, 0, 0, 0, 0, 0, 0, 0};
    float bGh = 0.0f;
    if (h < 8) {
        const float* wrow = WG + h * 64;
#pragma unroll
        for (int e = 0; e < 8; e++) {
            bf0[e] = (short)f2b(wrow[ko + e]);
            bf1[e] = (short)f2b(wrow[32 + ko + e]);
        }
        bGh = bG[h];
    }
    __syncthreads();

#pragma unroll
    for (int tt = 0; tt < 4; tt++) {
        int mt = (wave << 2) + tt;
        int row = (mt << 4) + h;
        int rswz = (row & 7) << 4;
        short8 a0 = *(const short8*)(embs + (((row << 7) + (ko << 1)) ^ rswz));
        short8 a1 = *(const short8*)(embs + (((row << 7) + 64 + (ko << 1)) ^ rswz));
        f32x4 acc = {0.f, 0.f, 0.f, 0.f};
        acc = __builtin_amdgcn_mfma_f32_16x16x32_bf16(a0, bf0, acc, 0, 0, 0);
        acc = __builtin_amdgcn_mfma_f32_16x16x32_bf16(a1, bf1, acc, 0, 0, 0);

        if (h < 8) {
            int j0 = (jt << 8) + (mt << 4) + ((lane >> 4) << 2);
            float4 o;
            o.x = __logf(fmaxf(acc[0] + bGh, 1e-6f));
            o.y = __logf(fmaxf(acc[1] + bGh, 1e-6f));
            o.z = __logf(fmaxf(acc[2] + bGh, 1e-6f));
            o.w = __logf(fmaxf(acc[3] + bGh, 1e-6f));
            *(float4*)&out[((size_t)((b << 3) + h) << 18) + ((size_t)i << 9) + j0] = o;
        }
    }
}

// ---------- fused flash attention: S=0.125*QK^T + wglog, softmax, O=PV ----------
// One wave (64-thread block) per 16 q-rows of one (b,h). No barriers: K/V/bias
// go straight to registers; only the P-transpose uses a 2.2KB per-wave LDS
// round-trip ordered by lgkmcnt(0)+sched_barrier.
__global__ __launch_bounds__(64) void attn_k(const u16* __restrict__ Qb,
                                             const u16* __restrict__ Kb,
                                             const u16* __restrict__ VT,
                                             const float* __restrict__ Sf,
                                             u16* __restrict__ ATT) {
    __shared__ u16 Pl[16 * 68];        // [16 q][64 k] bf16, row stride 68 (conflict-free)
    const int lane = threadIdx.x;
    const int c = lane & 15, g = lane >> 4;
    const int bid = blockIdx.x;
    const int qb = bid & 31, bh = bid >> 5;      // consecutive blocks share (b,h) -> L2 K/V reuse
    const int b = bh >> 3, h = bh & 7;
    const int q0 = qb << 4;

    const u16* Qp = Qb + ((size_t)bh << 15);     // [512][64]
    const u16* Kp = Kb + ((size_t)bh << 15);     // [512][64]
    const u16* Vp = VT + ((size_t)bh << 15);     // [64][512]
    const float* Bp = Sf + ((size_t)bh << 18) + ((size_t)q0 << 9);

    short8 qf[2];
#pragma unroll
    for (int ks = 0; ks < 2; ks++)
        qf[ks] = *(const short8*)&Qp[(size_t)(q0 + c) * 64 + ks * 32 + g * 8];

    f32x4 o[4] = {};
    float m[4] = {-1e30f, -1e30f, -1e30f, -1e30f};
    float l[4] = {0.f, 0.f, 0.f, 0.f};

    for (int kt = 0; kt < 8; kt++) {
        const int k0 = kt << 6;
        short8 kf[4][2], vf[4][2];
#pragma unroll
        for (int jj = 0; jj < 4; jj++)
#pragma unroll
            for (int ks = 0; ks < 2; ks++) {
                kf[jj][ks] = *(const short8*)&Kp[(size_t)(k0 + jj * 16 + c) * 64 + ks * 32 + g * 8];
                vf[jj][ks] = *(const short8*)&Vp[(size_t)(jj * 16 + c) * 512 + k0 + ks * 32 + g * 8];
            }
        float bias[4][4];
#pragma unroll
        for (int jj = 0; jj < 4; jj++)
#pragma unroll
            for (int r = 0; r < 4; r++)
                bias[jj][r] = Bp[(size_t)(g * 4 + r) * 512 + k0 + jj * 16 + c];

        f32x4 sa[4] = {};
#pragma unroll
        for (int jj = 0; jj < 4; jj++)
#pragma unroll
            for (int ks = 0; ks < 2; ks++)
                sa[jj] = __builtin_amdgcn_mfma_f32_16x16x32_bf16(qf[ks], kf[jj][ks], sa[jj], 0, 0, 0);

        float s[4][4];
#pragma unroll
        for (int r = 0; r < 4; r++) {
#pragma unroll
            for (int jj = 0; jj < 4; jj++)
                s[jj][r] = sa[jj][r] * 0.125f + bias[jj][r];
            float v = fmaxf(fmaxf(s[0][r], s[1][r]), fmaxf(s[2][r], s[3][r]));
#pragma unroll
            for (int off = 1; off < 16; off <<= 1)
                v = fmaxf(v, __shfl_xor(v, off));
            float mn = fmaxf(m[r], v);
            float alpha = __expf(m[r] - mn);
            m[r] = mn;
            float rs = 0.f;
#pragma unroll
            for (int jj = 0; jj < 4; jj++) {
                float p = __expf(s[jj][r] - mn);
                s[jj][r] = p;
                rs += p;
            }
#pragma unroll
            for (int off = 1; off < 16; off <<= 1)
                rs += __shfl_xor(rs, off);
            l[r] = l[r] * alpha + rs;
#pragma unroll
            for (int jjo = 0; jjo < 4; jjo++)
                o[jjo][r] *= alpha;
        }

        // P -> LDS (transpose to A-frag layout), same-wave ordering via lgkmcnt
#pragma unroll
        for (int jj = 0; jj < 4; jj++)
#pragma unroll
            for (int r = 0; r < 4; r++)
                Pl[(g * 4 + r) * 68 + jj * 16 + c] = f2b(s[jj][r]);
        asm volatile("s_waitcnt lgkmcnt(0)" ::: "memory");
        __builtin_amdgcn_sched_barrier(0);

        short8 pa[2];
#pragma unroll
        for (int ks = 0; ks < 2; ks++)
            pa[ks] = *(const short8*)&Pl[c * 68 + ks * 32 + g * 8];
#pragma unroll
        for (int jjo = 0; jjo < 4; jjo++)
#pragma unroll
            for (int ks = 0; ks < 2; ks++)
                o[jjo] = __builtin_amdgcn_mfma_f32_16x16x32_bf16(pa[ks], vf[jjo][ks], o[jjo], 0, 0, 0);
        __builtin_amdgcn_sched_barrier(0);   // keep next tile's LDS writes behind these reads
    }

#pragma unroll
    for (int r = 0; r < 4; r++) {
        float inv = 1.0f / l[r];
        int row = q0 + g * 4 + r;
#pragma unroll
        for (int jjo = 0; jjo < 4; jjo++)
            ATT[(size_t)(((b << 9) + row) << 9) + (h << 6) + jjo * 16 + c] = f2b(o[jjo][r] * inv);
    }
}

// ---------- generic bf16 MFMA GEMM: C[M,N] = A[M,K] @ Bm[N,K]^T (+epilogue) ----------
// MODE 0: proj -> q/k bf16 [B,H,N,DK]   MODE 1: proj -> vT bf16 [B,H,DK,N]
// MODE 4: out -> f32 row-major [2048,512] (+bias)
template<int MODE>
__global__ __launch_bounds__(256) void gemm_k(const u16* __restrict__ A,
                                              const u16* __restrict__ Bm,
                                              const float* __restrict__ bias,
                                              void* __restrict__ outp) {
    constexpr int Kdim = 512, lda = 512, ldb = 512;

    __shared__ u16 As[64 * 32];
    __shared__ u16 Bs[64 * 32];

    const int t = threadIdx.x;
    const int wave = t >> 6, lane = t & 63;
    const int wr = wave >> 1, wc = wave & 1;
    const int m0 = blockIdx.y * 64, n0 = blockIdx.x * 64;

    f32x4 acc[2][2] = {};
    const int srow = t >> 2, scol = (t & 3) * 8;

    for (int k0 = 0; k0 < Kdim; k0 += 32) {
        *(u32x4*)&As[srow * 32 + scol] = *(const u32x4*)&A[(size_t)(m0 + srow) * lda + k0 + scol];
        *(u32x4*)&Bs[srow * 32 + scol] = *(const u32x4*)&Bm[(size_t)(n0 + srow) * ldb + k0 + scol];
        __syncthreads();

        short8 af[2], bfr[2];
#pragma unroll
        for (int i = 0; i < 2; i++)
            af[i] = *(const short8*)&As[(wr * 32 + i * 16 + (lane & 15)) * 32 + ((lane >> 4) << 3)];
#pragma unroll
        for (int jj = 0; jj < 2; jj++)
            bfr[jj] = *(const short8*)&Bs[(wc * 32 + jj * 16 + (lane & 15)) * 32 + ((lane >> 4) << 3)];
#pragma unroll
        for (int i = 0; i < 2; i++)
#pragma unroll
            for (int jj = 0; jj < 2; jj++)
                acc[i][jj] = __builtin_amdgcn_mfma_f32_16x16x32_bf16(af[i], bfr[jj], acc[i][jj], 0, 0, 0);
        __syncthreads();
    }

    u16*  outU = (u16*)outp;
    float* outF = (float*)outp;
#pragma unroll
    for (int i = 0; i < 2; i++) {
#pragma unroll
        for (int jj = 0; jj < 2; jj++) {
#pragma unroll
            for (int r = 0; r < 4; r++) {
                int row = m0 + wr * 32 + i * 16 + ((lane >> 4) << 2) + r;
                int col = n0 + wc * 32 + jj * 16 + (lane & 15);
                float v = acc[i][jj][r];
                if constexpr (MODE == 0) {
                    int b = row >> 9, rr = row & 511, h = col >> 6, d = col & 63;
                    outU[(size_t)((((b << 3) + h) << 9) + rr) * 64 + d] = f2b(v + bias[col]);
                } else if constexpr (MODE == 1) {
                    int b = row >> 9, rr = row & 511, h = col >> 6, d = col & 63;
                    outU[(size_t)((((b << 3) + h) << 6) + d) * 512 + rr] = f2b(v + bias[col]);
                } else {
                    outF[((size_t)row << 9) + col] = v + bias[col];
                }
            }
        }
    }
}

// ---------- launch ----------
extern "C" void kernel_launch(void* const* d_in, const int* in_sizes, int n_in,
                              void* d_out, int out_size, void* d_ws, size_t ws_size,
                              hipStream_t stream) {
    const float* inq = (const float*)d_in[0];
    const float* ink = (const float*)d_in[1];
    const float* inv = (const float*)d_in[2];
    const float* box = (const float*)d_in[3];
    const float* Wq  = (const float*)d_in[4];
    const float* bq  = (const float*)d_in[5];
    const float* Wk  = (const float*)d_in[6];
    const float* bk  = (const float*)d_in[7];
    const float* Wv  = (const float*)d_in[8];
    const float* bv  = (const float*)d_in[9];
    const float* Wo  = (const float*)d_in[10];
    const float* bo  = (const float*)d_in[11];
    const float* WG  = (const float*)d_in[12];
    const float* bG  = (const float*)d_in[13];

    u16* base = (u16*)d_ws;
    u16* XQ  = base;                 // 3 x 1,048,576 bf16
    u16* XK  = base + 1048576;
    u16* XV  = base + 2097152;
    u16* WQb = base + 3145728;       // 4 x 262,144 bf16
    u16* WKb = base + 3407872;
    u16* WVb = base + 3670016;
    u16* WOb = base + 3932160;
    u16* Qb  = base + 4194304;       // [B,H,N,64] bf16
    u16* Kb  = base + 5242880;       // [B,H,N,64] bf16
    u16* VT  = base + 6291456;       // [B,H,64,N] bf16
    u16* ATT = base + 7340032;       // [B,N,512] bf16
    float* Sf = (float*)(base + 8388608);        // [B,H,N,N] f32 wglog

    cvt_k<<<dim3(1024, 1, 3), 256, 0, stream>>>(inq, ink, inv, inq, XQ, 1048576);
    cvt_k<<<dim3(256, 1, 4), 256, 0, stream>>>(Wq, Wk, Wv, Wo, WQb, 262144);
    geom_k<<<dim3(2, 512, 4), 256, 0, stream>>>(box, WG, bG, Sf);

    gemm_k<0><<<dim3(8, 32, 1), 256, 0, stream>>>(XQ, WQb, bq, Qb);
    gemm_k<0><<<dim3(8, 32, 1), 256, 0, stream>>>(XK, WKb, bk, Kb);
    gemm_k<1><<<dim3(8, 32, 1), 256, 0, stream>>>(XV, WVb, bv, VT);

    attn_k<<<dim3(1024), 64, 0, stream>>>(Qb, Kb, VT, Sf, ATT);

    gemm_k<4><<<dim3(8, 32, 1), 256, 0, stream>>>(ATT, WOb, bo, d_out);
}